// Round 1
// baseline (51.717 us; speedup 1.0000x reference)
//
#include <hip/hip_runtime.h>
#include <stdint.h>

// Problem constants
#define NINq   512
#define DIMq   64
#define NHEADq 8
#define Bq     2
#define Nq     2048
#define MTOT   4096          // B*N rows
#define OUTF   512           // DIM*NHEAD
#define NCHUNK 16            // NHEAD*B
#define CHELEM 131072        // 2048*64 elements per chunk
#define NSPLIT 16

typedef __attribute__((ext_vector_type(4))) float   f32x4;
typedef __attribute__((ext_vector_type(8))) short   bh8;     // 8 bf16 in 4 VGPRs
typedef __attribute__((ext_vector_type(4))) unsigned short u16x4;
typedef unsigned short u16;

__device__ inline u16 f2bf(float f) {
    union { float f; uint32_t u; } v; v.f = f;
    uint32_t u = v.u;
    u += 0x7FFF + ((u >> 16) & 1);         // RNE
    return (u16)(u >> 16);
}
__device__ inline float bf2f(u16 h) {
    union { uint32_t u; float f; } v; v.u = ((uint32_t)h) << 16;
    return v.f;
}

__device__ inline void gload_lds16(const u16* g, u16* l) {
    __builtin_amdgcn_global_load_lds(
        (const __attribute__((address_space(1))) uint32_t*)g,
        (__attribute__((address_space(3)))       uint32_t*)l,
        16, 0, 0);
}

// ---------------- K0: convert x, Wq, Wk, Wv to bf16 ----------------
__global__ __launch_bounds__(256) void k0_convert(
        const float* __restrict__ x,
        const float* __restrict__ Wq,
        const float* __restrict__ Wk,
        const float* __restrict__ Wv,
        u16* __restrict__ xb, u16* __restrict__ Wb) {
    int idx = blockIdx.x * 256 + threadIdx.x;   // float4 index, 720896 total
    const float4* src; u16* dst; int off;
    if (idx < 524288) { src = (const float4*)x; dst = xb; off = idx; }
    else {
        int j = idx - 524288;
        int w = j >> 16;                        // 65536 float4 per W
        off = j & 65535;
        src = (const float4*)(w == 0 ? Wq : (w == 1 ? Wk : Wv));
        dst = Wb + w * (512 * 512);
    }
    float4 f = src[off];
    u16x4 o;
    o[0] = f2bf(f.x); o[1] = f2bf(f.y); o[2] = f2bf(f.z); o[3] = f2bf(f.w);
    *(u16x4*)(dst + off * 4) = o;
}

// ---------------- K1: QKV projection GEMM ----------------
// C[m,n] = sum_k xb[m,k] * W[n,k] + bias[n]   (gemm_bt), 128x128 tile, BK=64
__global__ __launch_bounds__(256) void k1_qkv(
        const u16* __restrict__ xb, const u16* __restrict__ Wb,
        const float* __restrict__ bq, const float* __restrict__ bk,
        const float* __restrict__ bv,
        u16* __restrict__ Qb, u16* __restrict__ Kb, u16* __restrict__ Vb) {
    __shared__ u16 lA[128 * 64];
    __shared__ u16 lB[128 * 64];
    const int tid  = threadIdx.x;
    const int lane = tid & 63, wid = tid >> 6;
    const int wrow = wid >> 1, wcol = wid & 1;
    const int nb = blockIdx.x, mb = blockIdx.y;
    const int w    = nb >> 2;
    const int nloc = (nb & 3) * 128;
    const u16*   W    = Wb + w * (512 * 512);
    const float* bias = (w == 0) ? bq : ((w == 1) ? bk : bv);
    u16*         out  = (w == 0) ? Qb : ((w == 1) ? Kb : Vb);
    const int m0 = mb * 128;

    f32x4 acc[4][4] = {};
    const int srow = tid >> 3;
    const int scol = (tid & 7) * 8;

    for (int kb = 0; kb < 8; ++kb) {
        __syncthreads();
        const int k0 = kb * 64;
#pragma unroll
        for (int it = 0; it < 4; ++it) {
            int r = it * 32 + srow;
            gload_lds16(xb + (size_t)(m0 + r) * 512 + k0 + scol,  lA + r * 64 + scol);
            gload_lds16(W  + (size_t)(nloc + r) * 512 + k0 + scol, lB + r * 64 + scol);
        }
        asm volatile("s_waitcnt vmcnt(0)" ::: "memory");
        __syncthreads();
#pragma unroll
        for (int ks = 0; ks < 2; ++ks) {
            const int kk = ks * 32 + (lane >> 4) * 8;
            bh8 a[4], b[4];
#pragma unroll
            for (int i = 0; i < 4; ++i) {
                a[i] = *(const bh8*)&lA[(wrow * 64 + i * 16 + (lane & 15)) * 64 + kk];
                b[i] = *(const bh8*)&lB[(wcol * 64 + i * 16 + (lane & 15)) * 64 + kk];
            }
#pragma unroll
            for (int i = 0; i < 4; ++i)
#pragma unroll
                for (int j = 0; j < 4; ++j)
                    acc[i][j] = __builtin_amdgcn_mfma_f32_16x16x32_bf16(a[i], b[j], acc[i][j], 0, 0, 0);
        }
    }
#pragma unroll
    for (int i = 0; i < 4; ++i) {
        const int row_base = m0 + wrow * 64 + i * 16 + ((lane >> 4) * 4);
#pragma unroll
        for (int j = 0; j < 4; ++j) {
            const int col = nloc + wcol * 64 + j * 16 + (lane & 15);
            const float bv_ = bias[col];
#pragma unroll
            for (int r = 0; r < 4; ++r)
                out[(size_t)(row_base + r) * 512 + col] = f2bf(acc[i][j][r] + bv_);
        }
    }
}

// ---------------- K2a: S partials = K^T V  (split-K, fp32 VALU) ----------------
// part[(c*16+s)][d][e] = sum_{r in split} V_c[r][d] * K_c[r][e]
__global__ __launch_bounds__(256) void k2a_partials(
        const u16* __restrict__ Kb, const u16* __restrict__ Vb,
        float* __restrict__ part) {
    __shared__ u16 lK[64 * 64];
    __shared__ u16 lV[64 * 64];
    const int tid = threadIdx.x;
    const int c = blockIdx.x >> 4;
    const int s = blockIdx.x & 15;
    const int e4 = (tid & 15) * 4;
    const int d4 = (tid >> 4) * 4;
    float acc[4][4] = {};
    const int base = c * CHELEM + s * 128 * 64;

    for (int step = 0; step < 2; ++step) {
        __syncthreads();
        const int tb = base + step * 4096;
        gload_lds16(Kb + tb + tid * 8,        lK + tid * 8);
        gload_lds16(Kb + tb + 2048 + tid * 8, lK + 2048 + tid * 8);
        gload_lds16(Vb + tb + tid * 8,        lV + tid * 8);
        gload_lds16(Vb + tb + 2048 + tid * 8, lV + 2048 + tid * 8);
        asm volatile("s_waitcnt vmcnt(0)" ::: "memory");
        __syncthreads();
#pragma unroll 8
        for (int r = 0; r < 64; ++r) {
            u16x4 ku = *(const u16x4*)&lK[r * 64 + e4];
            u16x4 vu = *(const u16x4*)&lV[r * 64 + d4];
            float kf[4] = {bf2f(ku[0]), bf2f(ku[1]), bf2f(ku[2]), bf2f(ku[3])};
            float vf[4] = {bf2f(vu[0]), bf2f(vu[1]), bf2f(vu[2]), bf2f(vu[3])};
#pragma unroll
            for (int j = 0; j < 4; ++j)
#pragma unroll
                for (int i = 0; i < 4; ++i)
                    acc[j][i] += vf[j] * kf[i];
        }
    }
    float* dst = part + (size_t)blockIdx.x * 4096;
#pragma unroll
    for (int j = 0; j < 4; ++j)
#pragma unroll
        for (int i = 0; i < 4; ++i)
            dst[(d4 + j) * 64 + (e4 + i)] = acc[j][i];
}

// ---------------- K2b: reduce partials, scale, scatter into BigS^T (bf16) ----------------
// BigS_t[bb][f][k]: row f (d=f/8,h=f%8) nonzero only at k=h*64+e, value scale*S_c[e][d]
__global__ __launch_bounds__(256) void k2b_bigs(
        const float* __restrict__ part, u16* __restrict__ BigS) {
    __shared__ float sv[4][64];
    const int tid = threadIdx.x;
    const int w = tid >> 6, lane = tid & 63;
    const int rg = blockIdx.x * 4 + w;          // 0..1023 = bb*512 + f
    const int f = rg & 511;
    const int bb = rg >> 9;
    const int d = f >> 3, h = f & 7;
    const int c = h * 2 + bb;
    float acc = 0.f;
#pragma unroll
    for (int s = 0; s < NSPLIT; ++s)
        acc += part[(size_t)(c * NSPLIT + s) * 4096 + d * 64 + lane];
    sv[w][lane] = acc * 0.125f;                 // scale = DIM^-0.5
    __syncthreads();
    u16 vals[8];
#pragma unroll
    for (int j = 0; j < 8; ++j) {
        int k = lane * 8 + j;
        vals[j] = ((k >> 6) == h) ? f2bf(sv[w][k & 63]) : (u16)0;
    }
    *(u16x4*)&BigS[(size_t)rg * 512 + lane * 8]     = *(u16x4*)&vals[0];
    *(u16x4*)&BigS[(size_t)rg * 512 + lane * 8 + 4] = *(u16x4*)&vals[4];
}

// ---------------- K3: out = A @ BigS_t^T per bb ----------------
// A[m][h*64+e] = Qb chunk(kb*2+bb) rows  (contiguous per k-block), output fp32
__global__ __launch_bounds__(256) void k3_out(
        const u16* __restrict__ Qb, const u16* __restrict__ BigS,
        float* __restrict__ outp) {
    __shared__ u16 lA[128 * 64];
    __shared__ u16 lB[128 * 64];
    const int tid  = threadIdx.x;
    const int lane = tid & 63, wid = tid >> 6;
    const int wrow = wid >> 1, wcol = wid & 1;
    const int nb = blockIdx.x, mb = blockIdx.y;
    const int m0 = mb * 128;
    const int bb = m0 >> 11;
    const int i0 = m0 & 2047;
    const int nloc = nb * 128;
    const u16* Bmat = BigS + (size_t)bb * (512 * 512);

    f32x4 acc[4][4] = {};
    const int srow = tid >> 3;
    const int scol = (tid & 7) * 8;
    const int soff = tid * 8;

    for (int kb = 0; kb < 8; ++kb) {
        __syncthreads();
        const u16* Abase = Qb + (size_t)(kb * 2 + bb) * CHELEM + i0 * 64;
#pragma unroll
        for (int it = 0; it < 4; ++it) {
            gload_lds16(Abase + it * 2048 + soff, lA + it * 2048 + soff);
            gload_lds16(Bmat + (size_t)(nloc + it * 32 + srow) * 512 + kb * 64 + scol,
                        lB + (it * 32 + srow) * 64 + scol);
        }
        asm volatile("s_waitcnt vmcnt(0)" ::: "memory");
        __syncthreads();
#pragma unroll
        for (int ks = 0; ks < 2; ++ks) {
            const int kk = ks * 32 + (lane >> 4) * 8;
            bh8 a[4], b[4];
#pragma unroll
            for (int i = 0; i < 4; ++i) {
                a[i] = *(const bh8*)&lA[(wrow * 64 + i * 16 + (lane & 15)) * 64 + kk];
                b[i] = *(const bh8*)&lB[(wcol * 64 + i * 16 + (lane & 15)) * 64 + kk];
            }
#pragma unroll
            for (int i = 0; i < 4; ++i)
#pragma unroll
                for (int j = 0; j < 4; ++j)
                    acc[i][j] = __builtin_amdgcn_mfma_f32_16x16x32_bf16(a[i], b[j], acc[i][j], 0, 0, 0);
        }
    }
#pragma unroll
    for (int i = 0; i < 4; ++i) {
        const int row_base = m0 + wrow * 64 + i * 16 + ((lane >> 4) * 4);
#pragma unroll
        for (int j = 0; j < 4; ++j) {
            const int col = nloc + wcol * 64 + j * 16 + (lane & 15);
#pragma unroll
            for (int r = 0; r < 4; ++r)
                outp[(size_t)(row_base + r) * 512 + col] = acc[i][j][r];
        }
    }
}

extern "C" void kernel_launch(void* const* d_in, const int* in_sizes, int n_in,
                              void* d_out, int out_size, void* d_ws, size_t ws_size,
                              hipStream_t stream) {
    const float* x  = (const float*)d_in[0];
    const float* Wq = (const float*)d_in[1];
    const float* bq = (const float*)d_in[2];
    const float* Wk = (const float*)d_in[3];
    const float* bk = (const float*)d_in[4];
    const float* Wv = (const float*)d_in[5];
    const float* bv = (const float*)d_in[6];
    float* outp = (float*)d_out;

    u16* xb = (u16*)d_ws;                 // 4096*512
    u16* Wb = xb + 2097152;               // 3*512*512
    u16* Qb = Wb + 786432;                // 4096*512
    u16* Kb = Qb + 2097152;
    u16* Vb = Kb + 2097152;
    float* part = (float*)(Vb + 2097152); // 16*16*4096 floats
    u16* BigS = (u16*)(part + 1048576);   // 2*512*512

    k0_convert<<<2816, 256, 0, stream>>>(x, Wq, Wk, Wv, xb, Wb);
    k1_qkv<<<dim3(12, 32), 256, 0, stream>>>(xb, Wb, bq, bk, bv, Qb, Kb, Vb);
    k2a_partials<<<256, 256, 0, stream>>>(Kb, Vb, part);
    k2b_bigs<<<256, 256, 0, stream>>>(part, BigS);
    k3_out<<<dim3(4, 32), 256, 0, stream>>>(Qb, BigS, outp);
}

// Round 2
// 47.563 us; speedup vs baseline: 1.0873x; 1.0873x over previous
//
#include <hip/hip_runtime.h>
#include <stdint.h>

// Problem constants
#define NINq   512
#define DIMq   64
#define NHEADq 8
#define Bq     2
#define Nq     2048
#define MTOT   4096          // B*N rows
#define CHELEM 131072        // 2048*64 elements per chunk
#define NSPLIT 16

typedef __attribute__((ext_vector_type(4))) float   f32x4;
typedef __attribute__((ext_vector_type(8))) short   bh8;     // 8 bf16 in 4 VGPRs
typedef __attribute__((ext_vector_type(4))) unsigned short u16x4;
typedef unsigned short u16;

__device__ inline u16 f2bf(float f) {
    union { float f; uint32_t u; } v; v.f = f;
    uint32_t u = v.u;
    u += 0x7FFF + ((u >> 16) & 1);         // RNE
    return (u16)(u >> 16);
}
__device__ inline float bf2f(u16 h) {
    union { uint32_t u; float f; } v; v.u = ((uint32_t)h) << 16;
    return v.f;
}

__device__ inline void gload_lds16(const u16* g, u16* l) {
    __builtin_amdgcn_global_load_lds(
        (const __attribute__((address_space(1))) uint32_t*)g,
        (__attribute__((address_space(3)))       uint32_t*)l,
        16, 0, 0);
}

// ---------------- K0: convert x, Wq, Wk, Wv to bf16 ----------------
__global__ __launch_bounds__(256) void k0_convert(
        const float* __restrict__ x,
        const float* __restrict__ Wq,
        const float* __restrict__ Wk,
        const float* __restrict__ Wv,
        u16* __restrict__ xb, u16* __restrict__ Wb) {
    int idx = blockIdx.x * 256 + threadIdx.x;   // float4 index, 720896 total
    const float4* src; u16* dst; int off;
    if (idx < 524288) { src = (const float4*)x; dst = xb; off = idx; }
    else {
        int j = idx - 524288;
        int w = j >> 16;                        // 65536 float4 per W
        off = j & 65535;
        src = (const float4*)(w == 0 ? Wq : (w == 1 ? Wk : Wv));
        dst = Wb + w * (512 * 512);
    }
    float4 f = src[off];
    u16x4 o;
    o[0] = f2bf(f.x); o[1] = f2bf(f.y); o[2] = f2bf(f.z); o[3] = f2bf(f.w);
    *(u16x4*)(dst + off * 4) = o;
}

// ---------------- K1: QKV projection GEMM ----------------
// C[m,n] = sum_k xb[m,k] * W[n,k] + bias[n]   (gemm_bt), 128x128 tile, BK=64
// Grid: 384 blocks 1D, XCD-swizzled so each XCD owns 4 mb-panels x all nb.
__global__ __launch_bounds__(256) void k1_qkv(
        const u16* __restrict__ xb, const u16* __restrict__ Wb,
        const float* __restrict__ bq, const float* __restrict__ bk,
        const float* __restrict__ bv,
        u16* __restrict__ Qb, u16* __restrict__ Kb, u16* __restrict__ Vb) {
    __shared__ u16 lA[128 * 64];
    __shared__ u16 lB[128 * 64];
    const int tid  = threadIdx.x;
    const int lane = tid & 63, wid = tid >> 6;
    const int wrow = wid >> 1, wcol = wid & 1;
    // XCD swizzle: 384 blocks, 8 XCDs, 48 consecutive per XCD
    const int flat = blockIdx.x;
    const int swz  = (flat & 7) * 48 + (flat >> 3);
    const int mb = swz / 12, nb = swz % 12;
    const int w    = nb >> 2;
    const int nloc = (nb & 3) * 128;
    const u16*   W    = Wb + w * (512 * 512);
    const float* bias = (w == 0) ? bq : ((w == 1) ? bk : bv);
    u16*         out  = (w == 0) ? Qb : ((w == 1) ? Kb : Vb);
    const int m0 = mb * 128;

    f32x4 acc[4][4] = {};
    const int srow = tid >> 3;
    const int scol = (tid & 7) * 8;

    for (int kb = 0; kb < 8; ++kb) {
        __syncthreads();
        const int k0 = kb * 64;
#pragma unroll
        for (int it = 0; it < 4; ++it) {
            int r = it * 32 + srow;
            gload_lds16(xb + (size_t)(m0 + r) * 512 + k0 + scol,  lA + r * 64 + scol);
            gload_lds16(W  + (size_t)(nloc + r) * 512 + k0 + scol, lB + r * 64 + scol);
        }
        asm volatile("s_waitcnt vmcnt(0)" ::: "memory");
        __syncthreads();
#pragma unroll
        for (int ks = 0; ks < 2; ++ks) {
            const int kk = ks * 32 + (lane >> 4) * 8;
            bh8 a[4], b[4];
#pragma unroll
            for (int i = 0; i < 4; ++i) {
                a[i] = *(const bh8*)&lA[(wrow * 64 + i * 16 + (lane & 15)) * 64 + kk];
                b[i] = *(const bh8*)&lB[(wcol * 64 + i * 16 + (lane & 15)) * 64 + kk];
            }
#pragma unroll
            for (int i = 0; i < 4; ++i)
#pragma unroll
                for (int j = 0; j < 4; ++j)
                    acc[i][j] = __builtin_amdgcn_mfma_f32_16x16x32_bf16(a[i], b[j], acc[i][j], 0, 0, 0);
        }
    }
#pragma unroll
    for (int i = 0; i < 4; ++i) {
        const int row_base = m0 + wrow * 64 + i * 16 + ((lane >> 4) * 4);
#pragma unroll
        for (int j = 0; j < 4; ++j) {
            const int col = nloc + wcol * 64 + j * 16 + (lane & 15);
            const float bv_ = bias[col];
#pragma unroll
            for (int r = 0; r < 4; ++r)
                out[(size_t)(row_base + r) * 512 + col] = f2bf(acc[i][j][r] + bv_);
        }
    }
}

// ---------------- K2a: P partials, P_c[d][e] = sum_r V_c[r][d] K_c[r][e] ----------------
__global__ __launch_bounds__(256) void k2a_partials(
        const u16* __restrict__ Kb, const u16* __restrict__ Vb,
        float* __restrict__ part) {
    __shared__ u16 lK[64 * 64];
    __shared__ u16 lV[64 * 64];
    const int tid = threadIdx.x;
    const int c = blockIdx.x >> 4;
    const int s = blockIdx.x & 15;
    const int e4 = (tid & 15) * 4;
    const int d4 = (tid >> 4) * 4;
    float acc[4][4] = {};
    const int base = c * CHELEM + s * 128 * 64;

    for (int step = 0; step < 2; ++step) {
        __syncthreads();
        const int tb = base + step * 4096;
        gload_lds16(Kb + tb + tid * 8,        lK + tid * 8);
        gload_lds16(Kb + tb + 2048 + tid * 8, lK + 2048 + tid * 8);
        gload_lds16(Vb + tb + tid * 8,        lV + tid * 8);
        gload_lds16(Vb + tb + 2048 + tid * 8, lV + 2048 + tid * 8);
        asm volatile("s_waitcnt vmcnt(0)" ::: "memory");
        __syncthreads();
#pragma unroll 8
        for (int r = 0; r < 64; ++r) {
            u16x4 ku = *(const u16x4*)&lK[r * 64 + e4];
            u16x4 vu = *(const u16x4*)&lV[r * 64 + d4];
            float kf[4] = {bf2f(ku[0]), bf2f(ku[1]), bf2f(ku[2]), bf2f(ku[3])};
            float vf[4] = {bf2f(vu[0]), bf2f(vu[1]), bf2f(vu[2]), bf2f(vu[3])};
#pragma unroll
            for (int j = 0; j < 4; ++j)
#pragma unroll
                for (int i = 0; i < 4; ++i)
                    acc[j][i] += vf[j] * kf[i];
        }
    }
    float* dst = part + (size_t)blockIdx.x * 4096;
#pragma unroll
    for (int j = 0; j < 4; ++j)
#pragma unroll
        for (int i = 0; i < 4; ++i)
            dst[(d4 + j) * 64 + (e4 + i)] = acc[j][i];
}

// ---------------- K2b: reduce partials + scale -> Pb bf16 [16][64][64] ----------------
__global__ __launch_bounds__(256) void k2b_reduce(
        const float* __restrict__ part, u16* __restrict__ Pb) {
    const int idx = blockIdx.x * 256 + threadIdx.x;   // 16384 groups of 4 elems
    const int c = idx >> 10;
    const int off = (idx & 1023) * 4;
    f32x4 acc = {0.f, 0.f, 0.f, 0.f};
#pragma unroll
    for (int s = 0; s < NSPLIT; ++s)
        acc += *(const f32x4*)&part[(size_t)(c * NSPLIT + s) * 4096 + off];
    u16x4 o;
#pragma unroll
    for (int j = 0; j < 4; ++j) o[j] = f2bf(acc[j] * 0.125f);   // scale = DIM^-0.5
    *(u16x4*)&Pb[c * 4096 + off] = o;
}

// ---------------- K3': out_c = Q_c @ Pb_c^T  (K=64 per head, no LDS) ----------------
// Block: 32 rows x all 512 cols. wave w: rows (w>>1)*16, d-half (w&1)*32.
// Lane's 8 head-values for fixed d are consecutive f=d*8..d*8+7 -> float4 x2 stores.
__global__ __launch_bounds__(256) void k3_out(
        const u16* __restrict__ Qb, const u16* __restrict__ Pb,
        float* __restrict__ outp) {
    const int tid = threadIdx.x;
    const int lane = tid & 63, w = tid >> 6;
    const int bb = blockIdx.x >> 6;          // 128 blocks: 64 row-blocks per bb
    const int ib = blockIdx.x & 63;
    const int i0 = ib * 32 + (w >> 1) * 16;  // row base within batch (A-frag rows)
    const int dbase = (w & 1) * 32;
    const int krow = lane & 15;
    const int koff = (lane >> 4) * 8;

    f32x4 acc[8][2] = {};                    // [head][nf]
#pragma unroll
    for (int h = 0; h < 8; ++h) {
        const int c = h * 2 + bb;
        const u16* Qc = Qb + (size_t)c * CHELEM;
        const u16* Pc = Pb + c * 4096;
#pragma unroll
        for (int ks = 0; ks < 2; ++ks) {
            bh8 a = *(const bh8*)&Qc[(i0 + krow) * 64 + ks * 32 + koff];
#pragma unroll
            for (int nf = 0; nf < 2; ++nf) {
                bh8 b = *(const bh8*)&Pc[(dbase + nf * 16 + krow) * 64 + ks * 32 + koff];
                acc[h][nf] = __builtin_amdgcn_mfma_f32_16x16x32_bf16(a, b, acc[h][nf], 0, 0, 0);
            }
        }
    }
    const int orow_base = bb * 2048 + ib * 32 + (w >> 1) * 16 + (lane >> 4) * 4;
#pragma unroll
    for (int nf = 0; nf < 2; ++nf) {
        const int d = dbase + nf * 16 + (lane & 15);
#pragma unroll
        for (int r = 0; r < 4; ++r) {
            f32x4 lo = {acc[0][nf][r], acc[1][nf][r], acc[2][nf][r], acc[3][nf][r]};
            f32x4 hi = {acc[4][nf][r], acc[5][nf][r], acc[6][nf][r], acc[7][nf][r]};
            float* dst = outp + (size_t)(orow_base + r) * 512 + d * 8;
            *(f32x4*)dst = lo;
            *(f32x4*)(dst + 4) = hi;
        }
    }
}

extern "C" void kernel_launch(void* const* d_in, const int* in_sizes, int n_in,
                              void* d_out, int out_size, void* d_ws, size_t ws_size,
                              hipStream_t stream) {
    const float* x  = (const float*)d_in[0];
    const float* Wq = (const float*)d_in[1];
    const float* bq = (const float*)d_in[2];
    const float* Wk = (const float*)d_in[3];
    const float* bk = (const float*)d_in[4];
    const float* Wv = (const float*)d_in[5];
    const float* bv = (const float*)d_in[6];
    float* outp = (float*)d_out;

    u16* xb = (u16*)d_ws;                 // 4096*512
    u16* Wb = xb + 2097152;               // 3*512*512
    u16* Qb = Wb + 786432;                // 4096*512
    u16* Kb = Qb + 2097152;
    u16* Vb = Kb + 2097152;
    float* part = (float*)(Vb + 2097152); // 256*4096 floats
    u16* Pb = (u16*)(part + 1048576);     // 16*64*64

    k0_convert<<<2816, 256, 0, stream>>>(x, Wq, Wk, Wv, xb, Wb);
    k1_qkv<<<384, 256, 0, stream>>>(xb, Wb, bq, bk, bv, Qb, Kb, Vb);
    k2a_partials<<<256, 256, 0, stream>>>(Kb, Vb, part);
    k2b_reduce<<<64, 256, 0, stream>>>(part, Pb);
    k3_out<<<128, 256, 0, stream>>>(Qb, Pb, outp);
}